// Round 5
// baseline (92.821 us; speedup 1.0000x reference)
//
#include <hip/hip_runtime.h>

#define N_NODES 10000
#define E_EDGES 640000
#define C 128
#define NBLK 64
#define TPB 512
#define EPB (E_EDGES / NBLK)     // 10000 edges per block (exact)
#define NCHUNK 157               // ceil(10000/64) nodes per block in reduce phase
#define NSUB 4                   // 512/128 channel-subsets

// Cumulative-arrival grid barrier. Requires all NBLK blocks co-resident
// (64 blocks x 80KB LDS x 512 thr on a 256-CU chip: trivially true).
// Counter is zeroed by a memset each call; targets are cumulative (k*NBLK)
// so no reset race. Release-add publishes prior global writes (device scope),
// acquire-spin + syncthreads makes them visible to the whole block.
__device__ __forceinline__ void grid_barrier(unsigned* cnt, unsigned target) {
    __syncthreads();
    if (threadIdx.x == 0) {
        __threadfence();
        __hip_atomic_fetch_add(cnt, 1u, __ATOMIC_RELEASE, __HIP_MEMORY_SCOPE_AGENT);
        while (__hip_atomic_load(cnt, __ATOMIC_ACQUIRE, __HIP_MEMORY_SCOPE_AGENT) < target)
            __builtin_amdgcn_s_sleep(2);
    }
    __syncthreads();
}

__global__ __launch_bounds__(TPB) void k_fused(
    const int* __restrict__ row, const int* __restrict__ col,
    const float* __restrict__ w,
    const float* __restrict__ W1, const float* __restrict__ b1,
    const float* __restrict__ W2, const float* __restrict__ b2,
    float* __restrict__ degp, float* __restrict__ tap, float* __restrict__ tbp,
    float* __restrict__ dinv, float* __restrict__ s1,
    float* __restrict__ gpart, unsigned* __restrict__ barcnt,
    float* __restrict__ out)
{
    __shared__ float smem[2 * N_NODES];          // 80 KB, reused across phases
    float* sa = smem;
    float* sb = smem + N_NODES;
    const int tid = threadIdx.x;
    const int bid = blockIdx.x;
    const int e0  = bid * EPB;

    // ---------- P0: per-block weighted-degree partial (scatter by col) ----------
    {
        float4 z = {0.f, 0.f, 0.f, 0.f};
        for (int i = tid; i < N_NODES / 4; i += TPB) ((float4*)sa)[i] = z;
        __syncthreads();
        const int4*   col4 = (const int4*)(col + e0);
        const float4* w4   = (const float4*)(w + e0);
        for (int k = tid; k < EPB / 4; k += TPB) {
            int4 cc = col4[k]; float4 ww = w4[k];
            atomicAdd(&sa[cc.x], ww.x);
            atomicAdd(&sa[cc.y], ww.y);
            atomicAdd(&sa[cc.z], ww.z);
            atomicAdd(&sa[cc.w], ww.w);
        }
        __syncthreads();
        float4* dst = (float4*)(degp + (size_t)bid * N_NODES);
        for (int i = tid; i < N_NODES / 4; i += TPB) dst[i] = ((const float4*)sa)[i];
    }
    grid_barrier(barcnt, 1u * NBLK);

    // ---------- P1: fold deg -> dinv (blocks 0..19); block 63: s1 = colsum(W1) ----
    {
        int i = bid * TPB + tid;                 // thread-linear node id
        if (i < N_NODES) {
            float d = 1.0f;                      // self-loop weight
            #pragma unroll 16
            for (int b = 0; b < NBLK; ++b) d += degp[(size_t)b * N_NODES + i];
            dinv[i] = rsqrtf(d);
        }
        if (bid == NBLK - 1 && tid < C) {
            float s = 0.0f;
            #pragma unroll 16
            for (int k = 0; k < C; ++k) s += W1[k * C + tid];  // coalesced across tid
            s1[tid] = s;
        }
    }
    grid_barrier(barcnt, 2u * NBLK);

    // ---------- P2: per-block t_a (by col) / t_b (by row) partials ----------
    {
        float4 z = {0.f, 0.f, 0.f, 0.f};
        for (int i = tid; i < (2 * N_NODES) / 4; i += TPB) ((float4*)smem)[i] = z;
        __syncthreads();
        const int4*   row4 = (const int4*)(row + e0);
        const int4*   col4 = (const int4*)(col + e0);
        const float4* w4   = (const float4*)(w + e0);
        for (int k = tid; k < EPB / 4; k += TPB) {
            int4 rr = row4[k]; int4 cc = col4[k]; float4 ww = w4[k];
            atomicAdd(&sa[cc.x], ww.x * dinv[rr.x]);
            atomicAdd(&sb[rr.x], ww.x * dinv[cc.x]);
            atomicAdd(&sa[cc.y], ww.y * dinv[rr.y]);
            atomicAdd(&sb[rr.y], ww.y * dinv[cc.y]);
            atomicAdd(&sa[cc.z], ww.z * dinv[rr.z]);
            atomicAdd(&sb[rr.z], ww.z * dinv[cc.z]);
            atomicAdd(&sa[cc.w], ww.w * dinv[rr.w]);
            atomicAdd(&sb[rr.w], ww.w * dinv[cc.w]);
        }
        __syncthreads();
        float4* da = (float4*)(tap + (size_t)bid * N_NODES);
        float4* db = (float4*)(tbp + (size_t)bid * N_NODES);
        for (int i = tid; i < N_NODES / 4; i += TPB) {
            da[i] = ((const float4*)sa)[i];
            db[i] = ((const float4*)sb)[i];
        }
    }
    grid_barrier(barcnt, 3u * NBLK);

    // ---------- P3+P4: fold partials -> alpha/beta (LDS), channel reduce ----------
    {
        int i0 = bid * NCHUNK;
        int n  = min(NCHUNK, N_NODES - i0);
        for (int t = tid; t < n; t += TPB) {     // threads 0..156 only; coalesced loads
            int i = i0 + t;
            float ta = 0.0f, tb = 0.0f;
            #pragma unroll 16
            for (int b = 0; b < NBLK; ++b) {
                ta += tap[(size_t)b * N_NODES + i];
                tb += tbp[(size_t)b * N_NODES + i];
            }
            float di = dinv[i], self = di * di;
            sa[t] = fmaf(di, ta, self);          // alpha
            sb[t] = fmaf(di, tb, self);          // beta
        }
        __syncthreads();
        int j   = tid & (C - 1);
        int sub = tid >> 7;
        float s1j = s1[j], b1j = b1[j], acc = 0.0f;
        for (int t = sub; t < n; t += NSUB) {    // LDS broadcast-ish reads
            float h = fmaf(sa[t], s1j, b1j);
            acc += sb[t] * fmaxf(h, 0.0f);       // exact relu
        }
        gpart[(size_t)(bid * NSUB + sub) * C + j] = acc;
    }
    grid_barrier(barcnt, 4u * NBLK);

    // ---------- P5: block 0 folds gpart, matvec with W2, writes out ----------
    if (bid == 0) {
        int j   = tid & (C - 1);
        int sub = tid >> 7;
        float G = 0.0f;
        #pragma unroll 16
        for (int r = sub; r < NBLK * NSUB; r += NSUB) G += gpart[(size_t)r * C + j];
        sa[sub * C + j] = G;
        __syncthreads();
        if (tid < C) {
            sb[tid] = sa[tid] + sa[C + tid] + sa[2 * C + tid] + sa[3 * C + tid];
        }
        __syncthreads();
        if (tid < C) {
            float acc = 0.0f;
            #pragma unroll 16
            for (int k = 0; k < C; ++k) acc += sb[k] * W2[k * C + tid];
            out[tid] = acc * (1.0f / (float)N_NODES) + b2[tid];
        }
    }
}

extern "C" void kernel_launch(void* const* d_in, const int* in_sizes, int n_in,
                              void* d_out, int out_size, void* d_ws, size_t ws_size,
                              hipStream_t stream) {
    const int*   eidx = (const int*)d_in[1];
    const int*   row  = eidx;             // edge_index[0]
    const int*   col  = eidx + E_EDGES;   // edge_index[1]
    const float* w    = (const float*)d_in[2];
    const float* W1   = (const float*)d_in[3];
    const float* b1   = (const float*)d_in[4];
    const float* W2   = (const float*)d_in[5];
    const float* b2   = (const float*)d_in[6];
    float* out = (float*)d_out;
    float* ws  = (float*)d_ws;

    float* degp  = ws;                                   // NBLK * N
    float* tap   = degp + (size_t)NBLK * N_NODES;        // NBLK * N
    float* tbp   = tap  + (size_t)NBLK * N_NODES;        // NBLK * N
    float* dinv  = tbp  + (size_t)NBLK * N_NODES;        // N
    float* s1    = dinv + N_NODES;                       // C
    float* gpart = s1 + C;                               // NBLK*NSUB * C
    unsigned* barcnt = (unsigned*)(gpart + (size_t)NBLK * NSUB * C);

    hipMemsetAsync(barcnt, 0, 128, stream);              // zero grid-barrier state
    k_fused<<<NBLK, TPB, 0, stream>>>(row, col, w, W1, b1, W2, b2,
                                      degp, tap, tbp, dinv, s1, gpart, barcnt, out);
}

// Round 6
// 77.259 us; speedup vs baseline: 1.2014x; 1.2014x over previous
//
#include <hip/hip_runtime.h>

#define N_NODES 10000
#define E_EDGES 640000
#define C 128
#define NBLK 64
#define TPB 512
#define EPB (E_EDGES / NBLK)     // 10000 edges per block (exact)
#define NCHUNK 157               // ceil(10000/64) nodes per block in reduce phase

// ---- grid barrier, invalidation-free spin --------------------------------
// Arrive: release fetch_add at agent scope (performs the L2 writeback that
// publishes this block's prior global stores to the coherence point).
// Wait: RELAXED agent polls (routed to coherence point, no cache invalidate),
// one ACQUIRE fence on exit. Every 32nd poll uses an acquire load as
// livelock insurance in case relaxed polls were served from a stale cache.
__device__ __forceinline__ void bar(unsigned* c, unsigned tgt, bool wait) {
    __syncthreads();                       // drains this block's stores to L2
    if (threadIdx.x == 0) {
        __hip_atomic_fetch_add(c, 1u, __ATOMIC_RELEASE, __HIP_MEMORY_SCOPE_AGENT);
        if (wait) {
            int p = 0;
            for (;;) {
                unsigned v = __hip_atomic_load(c, __ATOMIC_RELAXED, __HIP_MEMORY_SCOPE_AGENT);
                if (v >= tgt) break;
                __builtin_amdgcn_s_sleep(4);
                if ((++p & 31) == 0) {
                    v = __hip_atomic_load(c, __ATOMIC_ACQUIRE, __HIP_MEMORY_SCOPE_AGENT);
                    if (v >= tgt) break;
                }
            }
            __builtin_amdgcn_fence(__ATOMIC_ACQUIRE, "agent");
        }
    }
    __syncthreads();
}

__global__ __launch_bounds__(TPB) void k_fused(
    const int* __restrict__ row, const int* __restrict__ col,
    const float* __restrict__ w,
    const float* __restrict__ W1, const float* __restrict__ b1,
    const float* __restrict__ W2, const float* __restrict__ b2,
    float* __restrict__ degp, float* __restrict__ tap, float* __restrict__ tbp,
    float* __restrict__ dinv, float* __restrict__ s1,
    unsigned* __restrict__ ctrl, float* __restrict__ g,
    float* __restrict__ out)
{
    __shared__ float smem[3 * N_NODES];          // 117 KB: sa | sb | sc(=sdinv)
    __shared__ int lastFlag;
    float* sa = smem;
    float* sb = smem + N_NODES;
    float* sc = smem + 2 * N_NODES;              // sdinv in P2, scratch later
    const int tid = threadIdx.x;
    const int bid = blockIdx.x;
    const int e0  = bid * EPB;

    // ---------- P0: per-block weighted-degree partial (scatter by col) ----------
    {
        float4 z = {0.f, 0.f, 0.f, 0.f};
        for (int i = tid; i < N_NODES / 4; i += TPB) ((float4*)sa)[i] = z;
        __syncthreads();
        const int4*   col4 = (const int4*)(col + e0);
        const float4* w4   = (const float4*)(w + e0);
        for (int k = tid; k < EPB / 4; k += TPB) {
            int4 cc = col4[k]; float4 ww = w4[k];
            atomicAdd(&sa[cc.x], ww.x);
            atomicAdd(&sa[cc.y], ww.y);
            atomicAdd(&sa[cc.z], ww.z);
            atomicAdd(&sa[cc.w], ww.w);
        }
        __syncthreads();
        float4* dst = (float4*)(degp + (size_t)bid * N_NODES);
        for (int i = tid; i < N_NODES / 4; i += TPB) dst[i] = ((const float4*)sa)[i];
    }
    // only fold blocks (0..19) and the s1 block (63) need to WAIT here
    const bool folder = (bid * TPB < N_NODES) || (bid == NBLK - 1);
    bar(ctrl + 0, NBLK, folder);

    // ---------- P1: fold deg -> dinv (blocks 0..19); block 63: s1 = colsum(W1) ----
    {
        int i = bid * TPB + tid;
        if (i < N_NODES) {
            float d = 1.0f;                      // self-loop weight
            #pragma unroll 16
            for (int b = 0; b < NBLK; ++b) d += degp[(size_t)b * N_NODES + i];
            dinv[i] = rsqrtf(d);
        }
        if (bid == NBLK - 1 && tid < C) {
            float s = 0.0f;
            #pragma unroll 16
            for (int k = 0; k < C; ++k) s += W1[k * C + tid];
            s1[tid] = s;
        }
    }
    bar(ctrl + 32, NBLK, true);                  // everyone needs dinv

    // ---------- P2: stage dinv in LDS; per-block t_a/t_b partials ----------
    {
        float4 z = {0.f, 0.f, 0.f, 0.f};
        for (int i = tid; i < (2 * N_NODES) / 4; i += TPB) ((float4*)smem)[i] = z;
        for (int i = tid; i < N_NODES / 4; i += TPB)
            ((float4*)sc)[i] = ((const float4*)dinv)[i];     // sdinv
        __syncthreads();
        const int4*   row4 = (const int4*)(row + e0);
        const int4*   col4 = (const int4*)(col + e0);
        const float4* w4   = (const float4*)(w + e0);
        for (int k = tid; k < EPB / 4; k += TPB) {
            int4 rr = row4[k]; int4 cc = col4[k]; float4 ww = w4[k];
            atomicAdd(&sa[cc.x], ww.x * sc[rr.x]);
            atomicAdd(&sb[rr.x], ww.x * sc[cc.x]);
            atomicAdd(&sa[cc.y], ww.y * sc[rr.y]);
            atomicAdd(&sb[rr.y], ww.y * sc[cc.y]);
            atomicAdd(&sa[cc.z], ww.z * sc[rr.z]);
            atomicAdd(&sb[rr.z], ww.z * sc[cc.z]);
            atomicAdd(&sa[cc.w], ww.w * sc[rr.w]);
            atomicAdd(&sb[rr.w], ww.w * sc[cc.w]);
        }
        __syncthreads();
        float4* da = (float4*)(tap + (size_t)bid * N_NODES);
        float4* db = (float4*)(tbp + (size_t)bid * N_NODES);
        for (int i = tid; i < N_NODES / 4; i += TPB) {
            da[i] = ((const float4*)sa)[i];
            db[i] = ((const float4*)sb)[i];
        }
    }
    bar(ctrl + 64, NBLK, true);

    // ---------- P3: parallel fold -> alpha/beta (LDS), channel reduce, g atomics ----
    {
        int i0 = bid * NCHUNK;
        if (tid < NCHUNK) {                       // waves 0-2: fold t_a
            int i = i0 + tid;
            if (i < N_NODES) {
                float ta = 0.0f;
                #pragma unroll 16
                for (int b = 0; b < NBLK; ++b) ta += tap[(size_t)b * N_NODES + i];
                float di = dinv[i];
                sa[tid] = fmaf(di, ta, di * di);  // alpha
            }
        } else if (tid >= 256 && tid < 256 + NCHUNK) {  // waves 4-6: fold t_b
            int t = tid - 256;
            int i = i0 + t;
            if (i < N_NODES) {
                float tb = 0.0f;
                #pragma unroll 16
                for (int b = 0; b < NBLK; ++b) tb += tbp[(size_t)b * N_NODES + i];
                float di = dinv[i];
                sb[t] = fmaf(di, tb, di * di);    // beta
            }
        }
        __syncthreads();
        int n   = min(NCHUNK, N_NODES - i0);
        int j   = tid & (C - 1);
        int sub = tid >> 7;
        float s1j = s1[j], b1j = b1[j], acc = 0.0f;
        for (int t = sub; t < n; t += 4) {        // LDS broadcast reads
            float h = fmaf(sa[t], s1j, b1j);
            acc += sb[t] * fmaxf(h, 0.0f);        // exact relu
        }
        sc[tid] = acc;                            // [sub][j]
        __syncthreads();
        if (tid < C) {
            float G = sc[tid] + sc[tid + 128] + sc[tid + 256] + sc[tid + 384];
            atomicAdd(&g[tid], G);                // device-scope, coherence point
        }
    }

    // ---------- P4: last-arriving block does the final matvec ----------
    __syncthreads();                              // g atomics issued (drained by syncthreads)
    if (tid == 0) {
        unsigned old = __hip_atomic_fetch_add(ctrl + 96, 1u, __ATOMIC_ACQ_REL,
                                              __HIP_MEMORY_SCOPE_AGENT);
        lastFlag = (old == NBLK - 1);
        if (lastFlag) __builtin_amdgcn_fence(__ATOMIC_ACQUIRE, "agent");
    }
    __syncthreads();
    if (lastFlag) {
        int j   = tid & (C - 1);
        int sub = tid >> 7;
        float acc = 0.0f;
        #pragma unroll 8
        for (int k = sub * 32; k < sub * 32 + 32; ++k)
            acc += g[k] * W2[k * C + j];          // g: broadcast, W2: coalesced
        sc[tid] = acc;
        __syncthreads();
        if (tid < C) {
            float r = sc[tid] + sc[tid + 128] + sc[tid + 256] + sc[tid + 384];
            out[tid] = r * (1.0f / (float)N_NODES) + b2[tid];
        }
    }
}

extern "C" void kernel_launch(void* const* d_in, const int* in_sizes, int n_in,
                              void* d_out, int out_size, void* d_ws, size_t ws_size,
                              hipStream_t stream) {
    const int*   eidx = (const int*)d_in[1];
    const int*   row  = eidx;             // edge_index[0]
    const int*   col  = eidx + E_EDGES;   // edge_index[1]
    const float* w    = (const float*)d_in[2];
    const float* W1   = (const float*)d_in[3];
    const float* b1   = (const float*)d_in[4];
    const float* W2   = (const float*)d_in[5];
    const float* b2   = (const float*)d_in[6];
    float* out = (float*)d_out;
    float* ws  = (float*)d_ws;

    float*    degp = ws;                                  // NBLK * N
    float*    tap  = degp + (size_t)NBLK * N_NODES;       // NBLK * N
    float*    tbp  = tap  + (size_t)NBLK * N_NODES;       // NBLK * N
    float*    dinv = tbp  + (size_t)NBLK * N_NODES;       // N
    float*    s1   = dinv + N_NODES;                      // C
    unsigned* ctrl = (unsigned*)(s1 + C);                 // 128 uints (4 counters, 128B apart)
    float*    g    = (float*)(ctrl + 128);                // C floats

    hipMemsetAsync(ctrl, 0, 128 * sizeof(unsigned) + C * sizeof(float), stream);
    k_fused<<<NBLK, TPB, 0, stream>>>(row, col, w, W1, b1, W2, b2,
                                      degp, tap, tbp, dinv, s1, ctrl, g, out);
}